// Round 1
// baseline (2401.727 us; speedup 1.0000x reference)
//
#include <hip/hip_runtime.h>
#include <cstdint>

#define S 64
#define SSZ (S*S)        // 4096  (one z-plane)
#define SV  (S*S*S)      // 262144 (one channel volume)
#define CH 64
#define NB 2

// ---------------------------------------------------------------------------
// Kernel 1: depthwise 5x5x5 conv, pad 2, + bias -> att1
// Block: 256 threads = 16 tx (each a 4-wide x strip) x 16 ty. y-tile = 16,
// full x width, z streamed with a 5-plane accumulator ring.
// ---------------------------------------------------------------------------
__global__ __launch_bounds__(256) void conv5_dw(const float* __restrict__ x,
                                                const float* __restrict__ w,   // [64][5][5][5]
                                                const float* __restrict__ bias,
                                                float* __restrict__ out) {
    const int ytile = blockIdx.x;           // 0..3
    const int bc    = blockIdx.y;           // 0..127 (b*64+c)
    const int c     = bc & (CH - 1);
    const int tid   = threadIdx.x;
    const int tx    = tid & 15;             // x = tx*4 + j
    const int ty    = tid >> 4;             // 0..15
    const int y0    = ytile * 16;

    const float* __restrict__ xin = x + (size_t)bc * SV;
    float* __restrict__ o         = out + (size_t)bc * SV;
    const float* __restrict__ wc  = w + c * 125;
    const float bv = bias[c];

    __shared__ float plane[20][68];         // rows gy = y0-2 .. y0+17, cols gx = -2..65

    float acc[5][4];
#pragma unroll
    for (int s = 0; s < 5; ++s)
#pragma unroll
        for (int j = 0; j < 4; ++j) acc[s][j] = 0.f;

    for (int zp = 0; zp < S; ++zp) {
        __syncthreads();
        // stage input plane zp (zero-padded halo)
        for (int idx = tid; idx < 20 * 68; idx += 256) {
            int r   = idx / 68;
            int col = idx - r * 68;
            int gy  = y0 - 2 + r;
            int gx  = col - 2;
            float v = 0.f;
            if (gy >= 0 && gy < S && gx >= 0 && gx < S)
                v = xin[zp * SSZ + gy * S + gx];
            plane[r][col] = v;
        }
        __syncthreads();

        // slot s holds output plane (zp-2+s); it receives weight kz = 4 - s
#pragma unroll
        for (int ky = 0; ky < 5; ++ky) {
            const float* row = &plane[ty + ky][tx * 4];
            float rr[8];
#pragma unroll
            for (int q = 0; q < 8; ++q) rr[q] = row[q];
#pragma unroll
            for (int s = 0; s < 5; ++s) {
                const float* wk = wc + (4 - s) * 25 + ky * 5;
#pragma unroll
                for (int kx = 0; kx < 5; ++kx) {
                    float wv = wk[kx];
                    acc[s][0] += wv * rr[kx + 0];
                    acc[s][1] += wv * rr[kx + 1];
                    acc[s][2] += wv * rr[kx + 2];
                    acc[s][3] += wv * rr[kx + 3];
                }
            }
        }

        int zo = zp - 2;                    // completed output plane
        if (zo >= 0) {
            float* orow = o + zo * SSZ + (y0 + ty) * S + tx * 4;
#pragma unroll
            for (int j = 0; j < 4; ++j) orow[j] = acc[0][j] + bv;
        }
        // shift ring
#pragma unroll
        for (int s = 0; s < 4; ++s)
#pragma unroll
            for (int j = 0; j < 4; ++j) acc[s][j] = acc[s + 1][j];
#pragma unroll
        for (int j = 0; j < 4; ++j) acc[4][j] = 0.f;
    }
    // flush output planes 62, 63
    {
        float* orow = o + 62 * SSZ + (y0 + ty) * S + tx * 4;
#pragma unroll
        for (int j = 0; j < 4; ++j) orow[j] = acc[0][j] + bv;
        orow = o + 63 * SSZ + (y0 + ty) * S + tx * 4;
#pragma unroll
        for (int j = 0; j < 4; ++j) orow[j] = acc[1][j] + bv;
    }
}

// ---------------------------------------------------------------------------
// Kernel 2: depthwise 7x7x7 conv, dilation 3, pad 9, + bias -> att2
// Block: 384 threads = 24 xgroups x 16 ty. Each block handles one z-residue
// class (z ≡ rz mod 3) and streams its ~21 input planes with a 7-slot ring.
// xgroup t: rx=t%3, i=t/3; outputs x = rx + 9i + 3j (j=0..2, masked at x>=64).
// ---------------------------------------------------------------------------
__global__ __launch_bounds__(384) void conv7_dil(const float* __restrict__ in,
                                                 const float* __restrict__ w,   // [64][7][7][7]
                                                 const float* __restrict__ bias,
                                                 float* __restrict__ out) {
    const int ytile = blockIdx.x;           // 0..3
    const int rz    = blockIdx.y;           // 0..2
    const int bc    = blockIdx.z;           // 0..127
    const int c     = bc & (CH - 1);
    const int tid   = threadIdx.x;
    const int t     = tid % 24;
    const int ty    = tid / 24;             // 0..15
    const int rx    = t % 3;
    const int ig    = t / 3;                // 0..7
    const int xb    = rx + 9 * ig;          // base output x (outputs xb, xb+3, xb+6)
    const int y0    = ytile * 16;

    const float* __restrict__ xin = in + (size_t)bc * SV;
    float* __restrict__ o         = out + (size_t)bc * SV;
    const float* __restrict__ wc  = w + c * 343;
    const float bv = bias[c];

    __shared__ float plane[34][90];         // rows gy = y0-9..y0+24, cols gx = -9..80

    float acc[7][3];
#pragma unroll
    for (int s = 0; s < 7; ++s)
#pragma unroll
        for (int j = 0; j < 3; ++j) acc[s][j] = 0.f;

    const int nz = (S - rz + 2) / 3;        // number of planes in this residue class
    for (int ii = 0; ii < nz; ++ii) {
        const int zi = rz + 3 * ii;
        __syncthreads();
        for (int idx = tid; idx < 34 * 90; idx += 384) {
            int r   = idx / 90;
            int col = idx - r * 90;
            int gy  = y0 - 9 + r;
            int gx  = col - 9;
            float v = 0.f;
            if (gy >= 0 && gy < S && gx >= 0 && gx < S)
                v = xin[zi * SSZ + gy * S + gx];
            plane[r][col] = v;
        }
        __syncthreads();

        // slot s holds output plane p = zi - 9 + 3s; receives weight kz = 6 - s
#pragma unroll
        for (int ky = 0; ky < 7; ++ky) {
            const float* row = &plane[ty + 3 * ky][xb];
            float rr[9];
#pragma unroll
            for (int q = 0; q < 9; ++q) rr[q] = row[3 * q];
#pragma unroll
            for (int s = 0; s < 7; ++s) {
                const float* wk = wc + (6 - s) * 49 + ky * 7;
#pragma unroll
                for (int kx = 0; kx < 7; ++kx) {
                    float wv = wk[kx];
                    acc[s][0] += wv * rr[kx + 0];
                    acc[s][1] += wv * rr[kx + 1];
                    acc[s][2] += wv * rr[kx + 2];
                }
            }
        }

        int p = zi - 9;                     // completed output plane
        if (p >= 0) {
            float* obase = o + p * SSZ + (y0 + ty) * S;
#pragma unroll
            for (int j = 0; j < 3; ++j) {
                int xx = xb + 3 * j;
                if (xx < S) obase[xx] = acc[0][j] + bv;
            }
        }
#pragma unroll
        for (int s = 0; s < 6; ++s)
#pragma unroll
            for (int j = 0; j < 3; ++j) acc[s][j] = acc[s + 1][j];
#pragma unroll
        for (int j = 0; j < 3; ++j) acc[6][j] = 0.f;
    }
    // flush last three output planes: zl-6, zl-3, zl  (zl = rz + 3*(nz-1))
    const int zl = rz + 3 * (nz - 1);
#pragma unroll
    for (int f = 0; f < 3; ++f) {
        int p = zl - 6 + 3 * f;
        if (p >= 0) {
            float* obase = o + p * SSZ + (y0 + ty) * S;
#pragma unroll
            for (int j = 0; j < 3; ++j) {
                int xx = xb + 3 * j;
                if (xx < S) obase[xx] = acc[f][j] + bv;
            }
        }
    }
}

// ---------------------------------------------------------------------------
// Kernel 3: channel mean & max over the 128 channels of [att1; att2]
// pooled layout: [B][2][64^3]  (ch0 = avg, ch1 = max)
// ---------------------------------------------------------------------------
__global__ __launch_bounds__(256) void reduce_ch(const float* __restrict__ att1,
                                                 const float* __restrict__ att2,
                                                 float* __restrict__ pooled) {
    const int idx = blockIdx.x * 256 + threadIdx.x;    // over NB*SV/4
    const int e   = idx * 4;
    const int b   = e >> 18;                           // SV = 2^18
    const int s   = e & (SV - 1);
    const float4* a1 = (const float4*)(att1 + (size_t)b * CH * SV + s);
    const float4* a2 = (const float4*)(att2 + (size_t)b * CH * SV + s);
    const int stride = SV / 4;

    float4 sum = make_float4(0.f, 0.f, 0.f, 0.f);
    float4 mx  = make_float4(-3.4e38f, -3.4e38f, -3.4e38f, -3.4e38f);
#pragma unroll 8
    for (int c = 0; c < CH; ++c) {
        float4 v1 = a1[c * stride];
        float4 v2 = a2[c * stride];
        sum.x += v1.x + v2.x; sum.y += v1.y + v2.y;
        sum.z += v1.z + v2.z; sum.w += v1.w + v2.w;
        mx.x = fmaxf(mx.x, fmaxf(v1.x, v2.x)); mx.y = fmaxf(mx.y, fmaxf(v1.y, v2.y));
        mx.z = fmaxf(mx.z, fmaxf(v1.z, v2.z)); mx.w = fmaxf(mx.w, fmaxf(v1.w, v2.w));
    }
    const float inv = 1.f / 128.f;
    sum.x *= inv; sum.y *= inv; sum.z *= inv; sum.w *= inv;
    *(float4*)(pooled + (size_t)b * 2 * SV + s)      = sum;
    *(float4*)(pooled + (size_t)b * 2 * SV + SV + s) = mx;
}

// ---------------------------------------------------------------------------
// Kernel 4: gate = sigmoid(conv3d(pooled, ws, pad 3) + bs)   [B][2][64^3]
// One block per (z, ytile of 8, b). Threads: 16 tx (4-wide strips) x 8 ty x 2 oc.
// ---------------------------------------------------------------------------
__global__ __launch_bounds__(256) void gate_conv(const float* __restrict__ pooled,
                                                 const float* __restrict__ wsg,  // [2][2][7][7][7]
                                                 const float* __restrict__ bs,
                                                 float* __restrict__ gate) {
    const int zc  = blockIdx.x;             // 0..63
    const int yt  = blockIdx.y;             // 0..7
    const int b   = blockIdx.z;             // 0..1
    const int tid = threadIdx.x;
    const int tx  = tid & 15;
    const int ty  = (tid >> 4) & 7;
    const int oc  = __builtin_amdgcn_readfirstlane(tid >> 7);
    const int y0  = yt * 8;

    __shared__ float sm[2][7][14][72];      // [ic][kz][row: y0-3..y0+10][col: x -3..66 (+pad)]

    const float* __restrict__ pb = pooled + (size_t)b * 2 * SV;
    for (int idx = tid; idx < 2 * 7 * 14 * 70; idx += 256) {
        int ic   = idx / (7 * 14 * 70);
        int rem  = idx - ic * (7 * 14 * 70);
        int kz   = rem / (14 * 70);
        int rem2 = rem - kz * (14 * 70);
        int r    = rem2 / 70;
        int col  = rem2 - r * 70;
        int gz = zc + kz - 3, gy = y0 + r - 3, gx = col - 3;
        float v = 0.f;
        if (gz >= 0 && gz < S && gy >= 0 && gy < S && gx >= 0 && gx < S)
            v = pb[ic * SV + gz * SSZ + gy * S + gx];
        sm[ic][kz][r][col] = v;
    }
    __syncthreads();

    float acc[4] = {0.f, 0.f, 0.f, 0.f};
    const float* __restrict__ wo = wsg + oc * 686;
    for (int ic = 0; ic < 2; ++ic)
        for (int kz = 0; kz < 7; ++kz) {
#pragma unroll
            for (int ky = 0; ky < 7; ++ky) {
                const float* row = &sm[ic][kz][ty + ky][tx * 4];
                float rr[10];
#pragma unroll
                for (int q = 0; q < 10; ++q) rr[q] = row[q];
                const float* wr = wo + ic * 343 + kz * 49 + ky * 7;
#pragma unroll
                for (int kx = 0; kx < 7; ++kx) {
                    float wv = wr[kx];
                    acc[0] += wv * rr[kx + 0];
                    acc[1] += wv * rr[kx + 1];
                    acc[2] += wv * rr[kx + 2];
                    acc[3] += wv * rr[kx + 3];
                }
            }
        }
    const float bvv = bs[oc];
    float* g = gate + ((size_t)b * 2 + oc) * SV + zc * SSZ + (y0 + ty) * S + tx * 4;
#pragma unroll
    for (int j = 0; j < 4; ++j)
        g[j] = 1.f / (1.f + __expf(-(acc[j] + bvv)));
}

// ---------------------------------------------------------------------------
// Kernel 5: out = att1*gate0 + att2*gate1 + x
// ---------------------------------------------------------------------------
__global__ __launch_bounds__(256) void combine(const float* __restrict__ att1,
                                               const float* __restrict__ att2,
                                               const float* __restrict__ x,
                                               const float* __restrict__ gate,
                                               float* __restrict__ out) {
    const int idx = blockIdx.x * 256 + threadIdx.x;    // over NB*CH*SV/4
    const int e   = idx * 4;
    const int b   = e >> 24;                           // CH*SV = 2^24
    const int s   = e & (SV - 1);
    float4 a1 = *(const float4*)(att1 + e);
    float4 a2 = *(const float4*)(att2 + e);
    float4 xv = *(const float4*)(x + e);
    float4 g0 = *(const float4*)(gate + (size_t)b * 2 * SV + s);
    float4 g1 = *(const float4*)(gate + (size_t)b * 2 * SV + SV + s);
    float4 r;
    r.x = a1.x * g0.x + a2.x * g1.x + xv.x;
    r.y = a1.y * g0.y + a2.y * g1.y + xv.y;
    r.z = a1.z * g0.z + a2.z * g1.z + xv.z;
    r.w = a1.w * g0.w + a2.w * g1.w + xv.w;
    *(float4*)(out + e) = r;
}

// ---------------------------------------------------------------------------
extern "C" void kernel_launch(void* const* d_in, const int* in_sizes, int n_in,
                              void* d_out, int out_size, void* d_ws, size_t ws_size,
                              hipStream_t stream) {
    const float* x   = (const float*)d_in[0];
    const float* w1  = (const float*)d_in[1];
    const float* b1  = (const float*)d_in[2];
    const float* w2  = (const float*)d_in[3];
    const float* b2  = (const float*)d_in[4];
    const float* wsg = (const float*)d_in[5];
    const float* bs  = (const float*)d_in[6];
    float* out = (float*)d_out;

    float* att1   = (float*)d_ws;                         // 2*64*SV floats
    float* att2   = att1 + (size_t)NB * CH * SV;          // 2*64*SV floats
    float* pooled = att2 + (size_t)NB * CH * SV;          // 2*2*SV floats
    float* gate   = pooled + (size_t)NB * 2 * SV;         // 2*2*SV floats

    conv5_dw <<<dim3(4, NB * CH), 256, 0, stream>>>(x, w1, b1, att1);
    conv7_dil<<<dim3(4, 3, NB * CH), 384, 0, stream>>>(att1, w2, b2, att2);
    reduce_ch<<<(NB * SV / 4) / 256, 256, 0, stream>>>(att1, att2, pooled);
    gate_conv<<<dim3(S, 8, NB), 256, 0, stream>>>(pooled, wsg, bs, gate);
    combine  <<<(NB * CH * SV / 4) / 256, 256, 0, stream>>>(att1, att2, x, gate, out);
}

// Round 2
// 2298.422 us; speedup vs baseline: 1.0449x; 1.0449x over previous
//
#include <hip/hip_runtime.h>
#include <cstdint>

#define S 64
#define SSZ (S*S)        // 4096  (one z-plane)
#define SV  (S*S*S)      // 262144 (one channel volume)
#define CH 64
#define NB 2

// ---------------------------------------------------------------------------
// Kernel 1: depthwise 5x5x5 conv, pad 2, + bias -> att1
// Grid (4 ytiles, 2 z-halves, 128 bc), 256 threads = 16 tx (4-wide strips) x 16 ty.
// Double-buffered plane staging (register relay), row stride 69 (odd -> the
// 4-rows-per-wave LDS read phases land in disjoint bank classes mod 4).
// ---------------------------------------------------------------------------
__global__ __launch_bounds__(256) void conv5_dw(const float* __restrict__ x,
                                                const float* __restrict__ w,   // [64][5][5][5]
                                                const float* __restrict__ bias,
                                                float* __restrict__ out) {
    const int ytile = blockIdx.x;           // 0..3
    const int zh    = blockIdx.y;           // 0..1
    const int bc    = blockIdx.z;           // 0..127
    const int c     = bc & (CH - 1);
    const int tid   = threadIdx.x;
    const int tx    = tid & 15;             // x = tx*4 + j
    const int ty    = tid >> 4;             // 0..15
    const int y0    = ytile * 16;
    const int zlo   = zh * 32, zhi = zlo + 32;
    const int zp0   = (zlo - 2 < 0) ? 0 : zlo - 2;
    const int zp1   = (zhi + 1 > S - 1) ? S - 1 : zhi + 1;

    const float* __restrict__ xin = x + (size_t)bc * SV;
    float* __restrict__ o         = out + (size_t)bc * SV;
    const float* __restrict__ wc  = w + c * 125;
    const float bv = bias[c];

    __shared__ float buf[2][20 * 69];       // rows gy = y0-2..y0+17, cols gx = -2..65, stride 69

    // staging precompute: 20*68 = 1360 elements, up to 6 per thread
    int lofs[6], gofs[6];
    unsigned vmask = 0;
#pragma unroll
    for (int k = 0; k < 6; ++k) {
        int idx = tid + k * 256;
        lofs[k] = -1; gofs[k] = 0;
        if (idx < 1360) {
            int r = idx / 68, col = idx - r * 68;
            lofs[k] = r * 69 + col;
            int gy = y0 - 2 + r, gx = col - 2;
            if (gy >= 0 && gy < S && gx >= 0 && gx < S) {
                gofs[k] = gy * S + gx;
                vmask |= 1u << k;
            }
        }
    }

    float acc[5][4];
#pragma unroll
    for (int s5 = 0; s5 < 5; ++s5)
#pragma unroll
        for (int j = 0; j < 4; ++j) acc[s5][j] = 0.f;

    float v[6];
#pragma unroll
    for (int k = 0; k < 6; ++k) {
        float t = xin[zp0 * SSZ + gofs[k]];
        v[k] = ((vmask >> k) & 1) ? t : 0.f;
    }
#pragma unroll
    for (int k = 0; k < 6; ++k) if (lofs[k] >= 0) buf[0][lofs[k]] = v[k];
    __syncthreads();

    int ibuf = 0;
    for (int zp = zp0; zp <= zp1; ++zp) {
        const float* __restrict__ cur = buf[ibuf];
        const int  znx  = zp + 1;
        const bool more = (znx <= zp1);
        if (more) {
#pragma unroll
            for (int k = 0; k < 6; ++k) {
                float t = xin[znx * SSZ + gofs[k]];
                v[k] = ((vmask >> k) & 1) ? t : 0.f;
            }
        }
        // compute on current plane; slot s holds output p = zp-2+s (weight kz = 4-s)
#pragma unroll
        for (int ky = 0; ky < 5; ++ky) {
            const float* rowp = &cur[(ty + ky) * 69 + tx * 4];
            float rr[8];
#pragma unroll
            for (int q = 0; q < 8; ++q) rr[q] = rowp[q];
#pragma unroll
            for (int s5 = 0; s5 < 5; ++s5) {
                const float* wk = wc + (4 - s5) * 25 + ky * 5;
#pragma unroll
                for (int kx = 0; kx < 5; ++kx) {
                    float wv = wk[kx];
                    acc[s5][0] = fmaf(wv, rr[kx + 0], acc[s5][0]);
                    acc[s5][1] = fmaf(wv, rr[kx + 1], acc[s5][1]);
                    acc[s5][2] = fmaf(wv, rr[kx + 2], acc[s5][2]);
                    acc[s5][3] = fmaf(wv, rr[kx + 3], acc[s5][3]);
                }
            }
        }
        if (more) {
#pragma unroll
            for (int k = 0; k < 6; ++k) if (lofs[k] >= 0) buf[ibuf ^ 1][lofs[k]] = v[k];
        }
        int p = zp - 2;
        if (p >= zlo && p < zhi) {
            float* orow = o + p * SSZ + (y0 + ty) * S + tx * 4;
#pragma unroll
            for (int j = 0; j < 4; ++j) orow[j] = acc[0][j] + bv;
        }
#pragma unroll
        for (int s5 = 0; s5 < 4; ++s5)
#pragma unroll
            for (int j = 0; j < 4; ++j) acc[s5][j] = acc[s5 + 1][j];
#pragma unroll
        for (int j = 0; j < 4; ++j) acc[4][j] = 0.f;
        __syncthreads();
        ibuf ^= 1;
    }
    // flush: slot s now holds p = zp1 - 1 + s
#pragma unroll
    for (int s5 = 0; s5 < 4; ++s5) {
        int p = zp1 - 1 + s5;
        if (p >= zlo && p < zhi) {
            float* orow = o + p * SSZ + (y0 + ty) * S + tx * 4;
#pragma unroll
            for (int j = 0; j < 4; ++j) orow[j] = acc[s5][j] + bv;
        }
    }
}

// ---------------------------------------------------------------------------
// Kernel 2: depthwise 7x7x7 conv, dilation 3, pad 9, + bias -> att2
// Grid (4 ytiles, 6 = 3 z-residues x 2 z-halves, 128 bc), 384 threads.
// Staged planes stored x-residue-GATHERED: row = [rx 0..2][t 0..29],
// value at gx = col-9 lives at (sub=col%3, t=col/3) -> compute reads are
// CONTIGUOUS 9-float windows. Double-buffered staging, one barrier/iter.
// ---------------------------------------------------------------------------
__global__ __launch_bounds__(384) void conv7_dil(const float* __restrict__ in,
                                                 const float* __restrict__ w,   // [64][7][7][7]
                                                 const float* __restrict__ bias,
                                                 float* __restrict__ out) {
    const int ytile = blockIdx.x;           // 0..3
    const int rz    = blockIdx.y % 3;       // z residue class
    const int zh    = blockIdx.y / 3;       // z half
    const int bc    = blockIdx.z;           // 0..127
    const int c     = bc & (CH - 1);
    const int tid   = threadIdx.x;
    const int t24   = tid % 24;
    const int ty    = tid / 24;             // 0..15
    const int rx    = t24 % 3;
    const int ig    = t24 / 3;              // 0..7
    const int xb    = rx + 9 * ig;          // outputs x = xb + 3j, j=0..2 (mask x>=64)
    const int y0    = ytile * 16;
    const int zlo   = zh * 32, zhi = zlo + 32;

    int lo = zlo - 9; if (lo < 0) lo = 0;
    int hi = zhi + 8; if (hi > S - 1) hi = S - 1;
    const int zi0     = lo + (((rz - lo) % 3) + 3) % 3;
    const int zi_last = hi - ((((hi - rz) % 3) + 3) % 3);

    const float* __restrict__ xin = in + (size_t)bc * SV;
    float* __restrict__ o         = out + (size_t)bc * SV;
    const float* __restrict__ wc  = w + c * 343;
    const float bv = bias[c];

    __shared__ float buf[2][34 * 90];       // rows gy = y0-9..y0+24, gathered cols

    // staging precompute: 34*90 = 3060 elements, up to 8 per thread
    int lofs[8], gofs[8];
    unsigned vmask = 0;
#pragma unroll
    for (int k = 0; k < 8; ++k) {
        int idx = tid + k * 384;
        lofs[k] = -1; gofs[k] = 0;
        if (idx < 3060) {
            int r = idx / 90, col = idx - r * 90;
            int tt = col / 3, sub = col - tt * 3;
            lofs[k] = r * 90 + sub * 30 + tt;
            int gy = y0 - 9 + r, gx = col - 9;
            if (gy >= 0 && gy < S && gx >= 0 && gx < S) {
                gofs[k] = gy * S + gx;
                vmask |= 1u << k;
            }
        }
    }

    float acc[7][3];
#pragma unroll
    for (int s7 = 0; s7 < 7; ++s7)
#pragma unroll
        for (int j = 0; j < 3; ++j) acc[s7][j] = 0.f;

    float v[8];
#pragma unroll
    for (int k = 0; k < 8; ++k) {
        float t = xin[zi0 * SSZ + gofs[k]];
        v[k] = ((vmask >> k) & 1) ? t : 0.f;
    }
#pragma unroll
    for (int k = 0; k < 8; ++k) if (lofs[k] >= 0) buf[0][lofs[k]] = v[k];
    __syncthreads();

    int ibuf = 0;
    for (int zi = zi0; zi <= zi_last; zi += 3) {
        const float* __restrict__ cur = buf[ibuf];
        const int  znx  = zi + 3;
        const bool more = (znx <= zi_last);
        if (more) {
#pragma unroll
            for (int k = 0; k < 8; ++k) {
                float t = xin[znx * SSZ + gofs[k]];
                v[k] = ((vmask >> k) & 1) ? t : 0.f;
            }
        }
        // compute; slot s holds output p = zi-9+3s (weight kz = 6-s)
#pragma unroll
        for (int ky = 0; ky < 7; ++ky) {
            const float* rowp = &cur[(ty + 3 * ky) * 90 + rx * 30 + 3 * ig];
            float rr[9];
#pragma unroll
            for (int q = 0; q < 9; ++q) rr[q] = rowp[q];
#pragma unroll
            for (int s7 = 0; s7 < 7; ++s7) {
                const float* wk = wc + (6 - s7) * 49 + ky * 7;
#pragma unroll
                for (int kx = 0; kx < 7; ++kx) {
                    float wv = wk[kx];
                    acc[s7][0] = fmaf(wv, rr[kx + 0], acc[s7][0]);
                    acc[s7][1] = fmaf(wv, rr[kx + 1], acc[s7][1]);
                    acc[s7][2] = fmaf(wv, rr[kx + 2], acc[s7][2]);
                }
            }
        }
        if (more) {
#pragma unroll
            for (int k = 0; k < 8; ++k) if (lofs[k] >= 0) buf[ibuf ^ 1][lofs[k]] = v[k];
        }
        int p = zi - 9;
        if (p >= zlo && p < zhi) {
            float* obase = o + p * SSZ + (y0 + ty) * S;
#pragma unroll
            for (int j = 0; j < 3; ++j) {
                int xx = xb + 3 * j;
                if (xx < S) obase[xx] = acc[0][j] + bv;
            }
        }
#pragma unroll
        for (int s7 = 0; s7 < 6; ++s7)
#pragma unroll
            for (int j = 0; j < 3; ++j) acc[s7][j] = acc[s7 + 1][j];
#pragma unroll
        for (int j = 0; j < 3; ++j) acc[6][j] = 0.f;
        __syncthreads();
        ibuf ^= 1;
    }
    // flush: slot s now holds p = zi_last - 6 + 3s
#pragma unroll
    for (int s7 = 0; s7 < 6; ++s7) {
        int p = zi_last - 6 + 3 * s7;
        if (p >= zlo && p < zhi) {
            float* obase = o + p * SSZ + (y0 + ty) * S;
#pragma unroll
            for (int j = 0; j < 3; ++j) {
                int xx = xb + 3 * j;
                if (xx < S) obase[xx] = acc[s7][j] + bv;
            }
        }
    }
}

// ---------------------------------------------------------------------------
// Kernel 3: channel mean & max over the 128 channels of [att1; att2]
// pooled layout: [B][2][64^3]  (ch0 = avg, ch1 = max)
// ---------------------------------------------------------------------------
__global__ __launch_bounds__(256) void reduce_ch(const float* __restrict__ att1,
                                                 const float* __restrict__ att2,
                                                 float* __restrict__ pooled) {
    const int idx = blockIdx.x * 256 + threadIdx.x;    // over NB*SV/4
    const int e   = idx * 4;
    const int b   = e >> 18;                           // SV = 2^18
    const int s   = e & (SV - 1);
    const float4* a1 = (const float4*)(att1 + (size_t)b * CH * SV + s);
    const float4* a2 = (const float4*)(att2 + (size_t)b * CH * SV + s);
    const int stride = SV / 4;

    float4 sum = make_float4(0.f, 0.f, 0.f, 0.f);
    float4 mx  = make_float4(-3.4e38f, -3.4e38f, -3.4e38f, -3.4e38f);
#pragma unroll 8
    for (int c = 0; c < CH; ++c) {
        float4 v1 = a1[c * stride];
        float4 v2 = a2[c * stride];
        sum.x += v1.x + v2.x; sum.y += v1.y + v2.y;
        sum.z += v1.z + v2.z; sum.w += v1.w + v2.w;
        mx.x = fmaxf(mx.x, fmaxf(v1.x, v2.x)); mx.y = fmaxf(mx.y, fmaxf(v1.y, v2.y));
        mx.z = fmaxf(mx.z, fmaxf(v1.z, v2.z)); mx.w = fmaxf(mx.w, fmaxf(v1.w, v2.w));
    }
    const float inv = 1.f / 128.f;
    sum.x *= inv; sum.y *= inv; sum.z *= inv; sum.w *= inv;
    *(float4*)(pooled + (size_t)b * 2 * SV + s)      = sum;
    *(float4*)(pooled + (size_t)b * 2 * SV + SV + s) = mx;
}

// ---------------------------------------------------------------------------
// Kernel 4: gate = sigmoid(conv3d(pooled, ws, pad 3) + bs)   [B][2][64^3]
// ---------------------------------------------------------------------------
__global__ __launch_bounds__(256) void gate_conv(const float* __restrict__ pooled,
                                                 const float* __restrict__ wsg,  // [2][2][7][7][7]
                                                 const float* __restrict__ bs,
                                                 float* __restrict__ gate) {
    const int zc  = blockIdx.x;             // 0..63
    const int yt  = blockIdx.y;             // 0..7
    const int b   = blockIdx.z;             // 0..1
    const int tid = threadIdx.x;
    const int tx  = tid & 15;
    const int ty  = (tid >> 4) & 7;
    const int oc  = tid >> 7;
    const int y0  = yt * 8;

    __shared__ float sm[2][7][14][72];

    const float* __restrict__ pb = pooled + (size_t)b * 2 * SV;
    for (int idx = tid; idx < 2 * 7 * 14 * 70; idx += 256) {
        int ic   = idx / (7 * 14 * 70);
        int rem  = idx - ic * (7 * 14 * 70);
        int kz   = rem / (14 * 70);
        int rem2 = rem - kz * (14 * 70);
        int r    = rem2 / 70;
        int col  = rem2 - r * 70;
        int gz = zc + kz - 3, gy = y0 + r - 3, gx = col - 3;
        float v = 0.f;
        if (gz >= 0 && gz < S && gy >= 0 && gy < S && gx >= 0 && gx < S)
            v = pb[ic * SV + gz * SSZ + gy * S + gx];
        sm[ic][kz][r][col] = v;
    }
    __syncthreads();

    float acc[4] = {0.f, 0.f, 0.f, 0.f};
    const float* __restrict__ wo = wsg + oc * 686;
    for (int ic = 0; ic < 2; ++ic)
        for (int kz = 0; kz < 7; ++kz) {
#pragma unroll
            for (int ky = 0; ky < 7; ++ky) {
                const float* row = &sm[ic][kz][ty + ky][tx * 4];
                float rr[10];
#pragma unroll
                for (int q = 0; q < 10; ++q) rr[q] = row[q];
                const float* wr = wo + ic * 343 + kz * 49 + ky * 7;
#pragma unroll
                for (int kx = 0; kx < 7; ++kx) {
                    float wv = wr[kx];
                    acc[0] = fmaf(wv, rr[kx + 0], acc[0]);
                    acc[1] = fmaf(wv, rr[kx + 1], acc[1]);
                    acc[2] = fmaf(wv, rr[kx + 2], acc[2]);
                    acc[3] = fmaf(wv, rr[kx + 3], acc[3]);
                }
            }
        }
    const float bvv = bs[oc];
    float* g = gate + ((size_t)b * 2 + oc) * SV + zc * SSZ + (y0 + ty) * S + tx * 4;
#pragma unroll
    for (int j = 0; j < 4; ++j)
        g[j] = 1.f / (1.f + __expf(-(acc[j] + bvv)));
}

// ---------------------------------------------------------------------------
// Kernel 5: out = att1*gate0 + att2*gate1 + x
// ---------------------------------------------------------------------------
__global__ __launch_bounds__(256) void combine(const float* __restrict__ att1,
                                               const float* __restrict__ att2,
                                               const float* __restrict__ x,
                                               const float* __restrict__ gate,
                                               float* __restrict__ out) {
    const int idx = blockIdx.x * 256 + threadIdx.x;    // over NB*CH*SV/4
    const int e   = idx * 4;
    const int b   = e >> 24;                           // CH*SV = 2^24
    const int s   = e & (SV - 1);
    float4 a1 = *(const float4*)(att1 + e);
    float4 a2 = *(const float4*)(att2 + e);
    float4 xv = *(const float4*)(x + e);
    float4 g0 = *(const float4*)(gate + (size_t)b * 2 * SV + s);
    float4 g1 = *(const float4*)(gate + (size_t)b * 2 * SV + SV + s);
    float4 r;
    r.x = a1.x * g0.x + a2.x * g1.x + xv.x;
    r.y = a1.y * g0.y + a2.y * g1.y + xv.y;
    r.z = a1.z * g0.z + a2.z * g1.z + xv.z;
    r.w = a1.w * g0.w + a2.w * g1.w + xv.w;
    *(float4*)(out + e) = r;
}

// ---------------------------------------------------------------------------
extern "C" void kernel_launch(void* const* d_in, const int* in_sizes, int n_in,
                              void* d_out, int out_size, void* d_ws, size_t ws_size,
                              hipStream_t stream) {
    const float* x   = (const float*)d_in[0];
    const float* w1  = (const float*)d_in[1];
    const float* b1  = (const float*)d_in[2];
    const float* w2  = (const float*)d_in[3];
    const float* b2  = (const float*)d_in[4];
    const float* wsg = (const float*)d_in[5];
    const float* bs  = (const float*)d_in[6];
    float* out = (float*)d_out;

    float* att1   = (float*)d_ws;                         // 2*64*SV floats
    float* att2   = att1 + (size_t)NB * CH * SV;          // 2*64*SV floats
    float* pooled = att2 + (size_t)NB * CH * SV;          // 2*2*SV floats
    float* gate   = pooled + (size_t)NB * 2 * SV;         // 2*2*SV floats

    conv5_dw <<<dim3(4, 2, NB * CH), 256, 0, stream>>>(x, w1, b1, att1);
    conv7_dil<<<dim3(4, 6, NB * CH), 384, 0, stream>>>(att1, w2, b2, att2);
    reduce_ch<<<(NB * SV / 4) / 256, 256, 0, stream>>>(att1, att2, pooled);
    gate_conv<<<dim3(S, 8, NB), 256, 0, stream>>>(pooled, wsg, bs, gate);
    combine  <<<(NB * CH * SV / 4) / 256, 256, 0, stream>>>(att1, att2, x, gate, out);
}